// Round 8
// baseline (821.866 us; speedup 1.0000x reference)
//
#include <hip/hip_runtime.h>

typedef unsigned short u16;
typedef unsigned int u32;

#define NB 32
#define NC 384
#define NH 12
#define DHD 32
#define HI 56
#define LQ 3136
#define HO 28
#define LK 784

typedef _Float16 half8 __attribute__((ext_vector_type(8)));
typedef float f32x4 __attribute__((ext_vector_type(4)));

__device__ __forceinline__ u16 f2h(float f) {
  // clamp: finite even if upstream ever feeds garbage (diagnosability)
  f = fminf(fmaxf(f, -60000.f), 60000.f);
  union { _Float16 h; u16 u; } v; v.h = (_Float16)f; return v.u;
}
__device__ __forceinline__ float h2f(u16 u) {
  union { u16 u; _Float16 h; } v; v.u = u; return (float)v.h;
}
__device__ __forceinline__ float gelu(float x) {
  return 0.5f * x * (1.0f + erff(x * 0.70710678118654752440f));
}

// ---------------- K1: depthwise 3x3 conv, all 3 branches -------------------
// branch 0 (stride 1): store f16 conv-q + stats; branches 1,2: store + stats.
__global__ __launch_bounds__(256) void k_dwconv(
    const float* __restrict__ x, const float* __restrict__ dwk,
    u16* __restrict__ cq, u16* __restrict__ ck, u16* __restrict__ cv,
    float* __restrict__ stats2)
{
  const int c = blockIdx.x, b = blockIdx.y, t = threadIdx.x;
  __shared__ float pl[LQ];
  __shared__ float ker[32];
  __shared__ float redw[24];
  const float* xp = x + ((size_t)(b * NC + c)) * LQ;
  for (int i = t; i < LQ / 4; i += 256)
    ((float4*)pl)[i] = ((const float4*)xp)[i];
  if (t < 27) ker[t] = dwk[t * NC + c];
  __syncthreads();
  float s0 = 0, s1 = 0, s2 = 0, s3 = 0, s4 = 0, s5 = 0;
  u16* oq = cq + ((size_t)(b * NC + c)) * LQ;
  for (int p = t; p < LQ; p += 256) {
    const int h = p / HI, w = p - h * HI;
    float a = 0.f;
#pragma unroll
    for (int kh = 0; kh < 3; kh++) {
      const int hh = h + kh - 1;
      if (hh < 0 || hh >= HI) continue;
#pragma unroll
      for (int kw = 0; kw < 3; kw++) {
        const int ww = w + kw - 1;
        if (ww < 0 || ww >= HI) continue;
        a += ker[kh * 3 + kw] * pl[hh * HI + ww];
      }
    }
    const u16 rq = f2h(a);
    oq[p] = rq;
    const float ar = h2f(rq);   // stats on stored (rounded) value
    s0 += ar; s1 += ar * ar;
  }
  u16* ok = ck + ((size_t)(b * NC + c)) * LK;
  u16* ov = cv + ((size_t)(b * NC + c)) * LK;
  for (int p = t; p < LK; p += 256) {
    const int h = p / HO, w = p - h * HO;
    float ak = 0.f, av = 0.f;
#pragma unroll
    for (int kh = 0; kh < 3; kh++) {
      const int hh = 2 * h + kh - 1;
      if (hh < 0 || hh >= HI) continue;
#pragma unroll
      for (int kw = 0; kw < 3; kw++) {
        const int ww = 2 * w + kw - 1;
        if (ww < 0 || ww >= HI) continue;
        const float xv = pl[hh * HI + ww];
        ak += ker[9 + kh * 3 + kw] * xv;
        av += ker[18 + kh * 3 + kw] * xv;
      }
    }
    const u16 rk = f2h(ak), rv = f2h(av);
    ok[p] = rk; ov[p] = rv;
    const float akr = h2f(rk), avr = h2f(rv);
    s2 += akr; s3 += akr * akr; s4 += avr; s5 += avr * avr;
  }
  const int lane = t & 63, wv = t >> 6;
#pragma unroll
  for (int off = 32; off > 0; off >>= 1) {
    s0 += __shfl_down(s0, off); s1 += __shfl_down(s1, off);
    s2 += __shfl_down(s2, off); s3 += __shfl_down(s3, off);
    s4 += __shfl_down(s4, off); s5 += __shfl_down(s5, off);
  }
  if (lane == 0) {
    redw[wv * 6 + 0] = s0; redw[wv * 6 + 1] = s1; redw[wv * 6 + 2] = s2;
    redw[wv * 6 + 3] = s3; redw[wv * 6 + 4] = s4; redw[wv * 6 + 5] = s5;
  }
  __syncthreads();
  if (t < 6) {
    const float tot = redw[t] + redw[6 + t] + redw[12 + t] + redw[18 + t];
    const int br = t >> 1, which = t & 1;
    atomicAdd(&stats2[((br * NC) + c) * 2 + which], tot);
  }
}

// ---------------- K2: fold BN2 into pointwise weights ----------------------
__global__ __launch_bounds__(128) void k_foldbn(
    const float* __restrict__ pww, const float* __restrict__ pwb,
    const float* __restrict__ g2, const float* __restrict__ b2,
    const float* __restrict__ stats2,
    u16* __restrict__ effw, float* __restrict__ effb)
{
  const int o = blockIdx.x, br = blockIdx.y, t = threadIdx.x;
  const float cnt = (br == 0) ? (float)(NB * LQ) : (float)(NB * LK);
  __shared__ float red[128];
  float bacc = 0.f;
  for (int c = t; c < NC; c += 128) {
    const float S = stats2[((br * NC) + c) * 2 + 0];
    const float S2 = stats2[((br * NC) + c) * 2 + 1];
    const float mu = S / cnt;
    const float var = fmaxf(S2 / cnt - mu * mu, 0.f);
    const float a = g2[br * NC + c] * rsqrtf(var + 1e-5f);
    const float bs = b2[br * NC + c] - mu * a;
    const size_t wi = (size_t)br * NC * NC + (size_t)o * NC + c;
    const float wvv = pww[wi];
    effw[wi] = f2h(wvv * a);
    bacc += wvv * bs;
  }
  red[t] = bacc;
  __syncthreads();
  for (int off = 64; off > 0; off >>= 1) {
    if (t < off) red[t] += red[t + off];
    __syncthreads();
  }
  if (t == 0) effb[br * NC + o] = red[0] + pwb[br * NC + o];
}

// ---------------- K3: pointwise GEMM + bias + GELU (all branches) ----------
// B-staging: 2 k's packed per u32 write (static data idx), XOR column swizzle
// col = k ^ ((n>>3 & 3)<<3) -> write conflicts 16/32-way -> 4-way; read stays
// a contiguous b128 with the inverse swizzle folded into the quad index.
__global__ __launch_bounds__(256) void k_pwgemm(
    const u16* __restrict__ Y, const u16* __restrict__ W,
    const float* __restrict__ bias, u16* __restrict__ Out, const int N)
{
  const int nb = blockIdx.x * 128;
  const int mb = blockIdx.y * 128;
  const int b = blockIdx.z;
  const int t = threadIdx.x;
  const int lane = t & 63;
  const int wm = ((t >> 6) & 1) * 64, wn = ((t >> 6) >> 1) * 64;
  const int quad = lane >> 4, r16 = lane & 15;
  __shared__ u16 As[128 * 40];
  __shared__ u16 Bs[128 * 40];
  const u16* Yb = Y + (size_t)b * NC * N;
  f32x4 acc[4][4];
#pragma unroll
  for (int i = 0; i < 4; i++)
#pragma unroll
    for (int j = 0; j < 4; j++) acc[i][j] = (f32x4){0.f, 0.f, 0.f, 0.f};

  for (int k0 = 0; k0 < NC; k0 += 32) {
#pragma unroll
    for (int ld = 0; ld < 2; ld++) {
      const int cid = t + ld * 256;
      const int r = cid >> 2, q4 = cid & 3;
      const uint4 u = *(const uint4*)(W + (size_t)(mb + r) * NC + k0 + q4 * 8);
      *(uint4*)(&As[r * 40 + q4 * 8]) = u;
    }
    // B tile: one pass, 256 threads; thread = (k-pair kk2, n-octet q4)
    {
      const int kk2 = t >> 4;          // 0..15
      const int q4 = t & 15;           // 0..15
      const int n = nb + q4 * 8;
      union { uint4 u; u16 s[8]; } v0, v1;
      if (n < N) {
        const u16* yr0 = Yb + (size_t)(k0 + 2 * kk2) * N + n;
        v0.u = *(const uint4*)yr0;
        v1.u = *(const uint4*)(yr0 + N);
      } else {
        v0.u = make_uint4(0u, 0u, 0u, 0u);
        v1.u = make_uint4(0u, 0u, 0u, 0u);
      }
      const int col = (2 * kk2) ^ ((q4 & 3) << 3);
      u16* bp = &Bs[(q4 * 8) * 40 + col];
#pragma unroll
      for (int j = 0; j < 8; j++) {
        const u32 w = (u32)v0.s[j] | ((u32)v1.s[j] << 16);
        *(u32*)(bp + j * 40) = w;
      }
    }
    __syncthreads();
    half8 af[4], bfv[4];
#pragma unroll
    for (int sm = 0; sm < 4; sm++)
      af[sm] = *(const half8*)(&As[(wm + sm * 16 + r16) * 40 + quad * 8]);
#pragma unroll
    for (int sn = 0; sn < 4; sn++) {
      const int n = wn + sn * 16 + r16;
      bfv[sn] = *(const half8*)(&Bs[n * 40 + (((quad ^ (n >> 3)) & 3) << 3)]);
    }
#pragma unroll
    for (int sm = 0; sm < 4; sm++)
#pragma unroll
      for (int sn = 0; sn < 4; sn++)
        acc[sm][sn] = __builtin_amdgcn_mfma_f32_16x16x32_f16(af[sm], bfv[sn], acc[sm][sn], 0, 0, 0);
    __syncthreads();
  }
  u16* Ob = Out + (size_t)b * NC * N;
#pragma unroll
  for (int sm = 0; sm < 4; sm++) {
#pragma unroll
    for (int sn = 0; sn < 4; sn++) {
      const int n = nb + wn + sn * 16 + r16;
      if (n >= N) continue;
#pragma unroll
      for (int r = 0; r < 4; r++) {
        const int m = mb + wm + sm * 16 + quad * 4 + r;
        const float vv = gelu(acc[sm][sn][r] + bias[m]);
        Ob[(size_t)m * N + n] = f2h(vv);
      }
    }
  }
}

// ---------------- K4a: column softmax over k tokens + kv = ks^T v ----------
__global__ __launch_bounds__(256) void k_kv(
    const u16* __restrict__ kb_, const u16* __restrict__ vb_,
    float* __restrict__ kv)
{
  const int h = blockIdx.x, b = blockIdx.y;
  const int t = threadIdx.x, lane = t & 63, wv = t >> 6;
  __shared__ float mZ[64];
  __shared__ float ekt[128 * 33];
  __shared__ float vtt[128 * 33];
  const u16* kb = kb_ + ((size_t)(b * NC + h * DHD)) * LK;
  const u16* vb = vb_ + ((size_t)(b * NC + h * DHD)) * LK;
#pragma unroll
  for (int rr = 0; rr < 8; rr++) {
    const int d = wv * 8 + rr;
    const u16* row = kb + (size_t)d * LK;
    float mx = -1e30f;
    for (int l = lane; l < LK; l += 64) mx = fmaxf(mx, h2f(row[l]));
#pragma unroll
    for (int off = 32; off > 0; off >>= 1) mx = fmaxf(mx, __shfl_xor(mx, off));
    float se = 0.f;
    for (int l = lane; l < LK; l += 64) se += __expf(h2f(row[l]) - mx);
#pragma unroll
    for (int off = 32; off > 0; off >>= 1) se += __shfl_xor(se, off);
    if (lane == 0) { mZ[d] = mx; mZ[32 + d] = se; }
  }
  __syncthreads();
  const int d = t >> 3, e4 = (t & 7) * 4;
  float a0 = 0, a1 = 0, a2 = 0, a3 = 0;
  const int rr = t >> 3;
  const int ls = (t & 7) * 16;
  const u16* krow = kb + (size_t)rr * LK;
  const u16* vrow = vb + (size_t)rr * LK;
  const float mrow = mZ[rr];
  for (int l0 = 0; l0 < LK; l0 += 128) {
#pragma unroll
    for (int j = 0; j < 16; j++) {
      const int l = l0 + ls + j;
      const bool ok = l < LK;
      ekt[(ls + j) * 33 + rr] = ok ? __expf(h2f(krow[l]) - mrow) : 0.f;
      vtt[(ls + j) * 33 + rr] = ok ? h2f(vrow[l]) : 0.f;
    }
    __syncthreads();
    for (int lc = 0; lc < 128; lc++) {
      const float kd = ekt[lc * 33 + d];
      a0 += kd * vtt[lc * 33 + e4 + 0];
      a1 += kd * vtt[lc * 33 + e4 + 1];
      a2 += kd * vtt[lc * 33 + e4 + 2];
      a3 += kd * vtt[lc * 33 + e4 + 3];
    }
    __syncthreads();
  }
  const float rz = 1.0f / mZ[32 + d];
  float* kvp = kv + ((size_t)(b * NH + h) * DHD + d) * DHD + e4;
  kvp[0] = a0 * rz; kvp[1] = a1 * rz; kvp[2] = a2 * rz; kvp[3] = a3 * rz;
}

// ---------------- K4b: q softmax + MFMA att + residual + BN1 stats ---------
// One token per thread (256 tokens/block). Softmax in regs; s split into
// f16 hi+lo pairs (exact in f32 MFMA accum: att = hi*khi + hi*klo + lo*khi,
// dropped lo*klo ~ 2^-24 rel). kv^T hi/lo built once per block. MFMA output
// (D rows = e via kvT A-operand, cols = token via ph B-operand; mapping
// identical to the verified k_pwgemm) transposed back through the dead
// p-buffer so the epilogue keeps the verified coalesced shape.
__global__ __launch_bounds__(256) void k_att(
    u16* __restrict__ qy, const float* __restrict__ x,
    const float* __restrict__ kv, const float* __restrict__ addw,
    float* __restrict__ stats1)
{
  const int chunk = blockIdx.x, h = blockIdx.y, b = blockIdx.z;
  const int t = threadIdx.x;
  const int lane = t & 63, wv = t >> 6;
  const int quad = lane >> 4, r16 = lane & 15;
  // per-wave 10240B region: [0,5120)=ph rows (64 x 40 u16), [5120,10240)=pl.
  // After MFMA the region is dead and reused as ytile f32 [64][33].
  __shared__ __align__(16) u16 pbuf[4][5120];
  __shared__ u16 kvThi[32 * 40];
  __shared__ u16 kvTlo[32 * 40];
  __shared__ float wred[4][64];

  // build kv^T hi/lo (f16 split), layout [e][d] pad 40
  const float* kvg = kv + (size_t)(b * NH + h) * (DHD * DHD);
  for (int i = t; i < DHD * DHD; i += 256) {
    const int e = i & 31, d = i >> 5;
    const float val = kvg[d * DHD + e];
    const _Float16 hi = (_Float16)val;
    const _Float16 lo = (_Float16)(val - (float)hi);
    union { _Float16 h; u16 u; } ch, cl; ch.h = hi; cl.h = lo;
    kvThi[e * 40 + d] = ch.u;
    kvTlo[e * 40 + d] = cl.u;
  }
  float w0 = fmaxf(addw[0], 0.f);
  float w1 = fmaxf(addw[1], 0.f);
  const float wsum = w0 + w1 + 1e-12f;
  w0 /= wsum; w1 /= wsum;

  // softmax for own token; write split-f16 s rows into own wave's pbuf
  const int tok = chunk * 256 + t;
  const bool valid = tok < LQ;
  const int tl = valid ? tok : (LQ - 1);
  const u16* qp = qy + ((size_t)(b * NC + h * DHD)) * LQ + tl;
  {
    float p[DHD];
    float mx = -1e30f;
#pragma unroll
    for (int d = 0; d < DHD; d++) { p[d] = h2f(qp[(size_t)d * LQ]); mx = fmaxf(mx, p[d]); }
    float se = 0.f;
#pragma unroll
    for (int d = 0; d < DHD; d++) { p[d] = __expf(p[d] - mx); se += p[d]; }
    const float rs = valid ? (1.0f / se) : 0.f;   // rs=0 -> zero columns
    u16* phr = &pbuf[wv][lane * 40];
    u16* plr = &pbuf[wv][2560 + lane * 40];
#pragma unroll
    for (int j = 0; j < 16; j++) {
      const float sa = p[2 * j] * rs, sb = p[2 * j + 1] * rs;
      const _Float16 ha = (_Float16)sa, hb = (_Float16)sb;
      const _Float16 la = (_Float16)(sa - (float)ha), lb = (_Float16)(sb - (float)hb);
      union { _Float16 h; u16 u; } ua, ub, va, vb2;
      ua.h = ha; ub.h = hb; va.h = la; vb2.h = lb;
      *(u32*)(phr + 2 * j) = (u32)ua.u | ((u32)ub.u << 16);
      *(u32*)(plr + 2 * j) = (u32)va.u | ((u32)vb2.u << 16);
    }
  }
  __syncthreads();

  // MFMA: D[e][token] per wave: 2 e-tiles x 4 token-tiles x 3 split terms
  f32x4 acc[2][4];
#pragma unroll
  for (int i = 0; i < 2; i++)
#pragma unroll
    for (int j = 0; j < 4; j++) acc[i][j] = (f32x4){0.f, 0.f, 0.f, 0.f};
  half8 ah[2], al[2];
#pragma unroll
  for (int et = 0; et < 2; et++) {
    ah[et] = *(const half8*)(&kvThi[(et * 16 + r16) * 40 + quad * 8]);
    al[et] = *(const half8*)(&kvTlo[(et * 16 + r16) * 40 + quad * 8]);
  }
  const u16* phb = &pbuf[wv][0];
#pragma unroll
  for (int tt = 0; tt < 4; tt++) {
    const half8 bh = *(const half8*)(phb + (tt * 16 + r16) * 40 + quad * 8);
    const half8 bl = *(const half8*)(phb + 2560 + (tt * 16 + r16) * 40 + quad * 8);
#pragma unroll
    for (int et = 0; et < 2; et++) {
      acc[et][tt] = __builtin_amdgcn_mfma_f32_16x16x32_f16(ah[et], bh, acc[et][tt], 0, 0, 0);
      acc[et][tt] = __builtin_amdgcn_mfma_f32_16x16x32_f16(ah[et], bl, acc[et][tt], 0, 0, 0);
      acc[et][tt] = __builtin_amdgcn_mfma_f32_16x16x32_f16(al[et], bh, acc[et][tt], 0, 0, 0);
    }
  }
  __syncthreads();   // all pbuf reads done block-wide; safe to reuse

  // transpose att back through own wave's region: ytile[token_local][e]
  float* yt = (float*)&pbuf[wv][0];
#pragma unroll
  for (int tt = 0; tt < 4; tt++)
#pragma unroll
    for (int et = 0; et < 2; et++)
#pragma unroll
      for (int r = 0; r < 4; r++)
        yt[(tt * 16 + r16) * 33 + et * 16 + quad * 4 + r] = acc[et][tt][r];
  __syncthreads();

  // epilogue (verified shape): lane owns token = chunk*256 + t
  u16* yp = qy + ((size_t)(b * NC + h * DHD)) * LQ + tl;
  const float* xp = x + ((size_t)(b * NC + h * DHD)) * LQ + tl;
#pragma unroll
  for (int e = 0; e < DHD; e++) {
    float v0 = 0.f;
    if (valid) {
      const float att = yt[lane * 33 + e];
      const float yv = w0 * att + w1 * xp[(size_t)e * LQ];
      const u16 r0 = f2h(yv);
      yp[(size_t)e * LQ] = r0;
      v0 = h2f(r0);     // stats on stored (rounded) value
    }
    float s = v0, q = v0 * v0;
#pragma unroll
    for (int off = 32; off > 0; off >>= 1) {
      s += __shfl_down(s, off); q += __shfl_down(q, off);
    }
    if (lane == 0) { wred[wv][e] = s; wred[wv][32 + e] = q; }
  }
  __syncthreads();
  if (t < 64) {
    const float tot = wred[0][t] + wred[1][t] + wred[2][t] + wred[3][t];
    const int e = t & 31, which = t >> 5;
    atomicAdd(&stats1[(h * DHD + e) * 2 + which], tot);
  }
}

// ---------------- K5: BN1 coefficients -------------------------------------
__global__ void k_bn1coef(const float* __restrict__ stats1,
                          const float* __restrict__ g1, const float* __restrict__ b1,
                          float* __restrict__ ss)
{
  const int c = threadIdx.x;
  if (c >= NC) return;
  const float cnt = (float)NB * (float)LQ;
  const float S = stats1[c * 2], S2 = stats1[c * 2 + 1];
  const float mu = S / cnt;
  const float var = fmaxf(S2 / cnt - mu * mu, 0.f);
  const float a = g1[c] * rsqrtf(var + 1e-5f);
  ss[c * 2] = a;
  ss[c * 2 + 1] = b1[c] - mu * a;
}

// ---------------- K6: apply BN1, write fp32 output -------------------------
__global__ __launch_bounds__(256) void k_bn1apply(
    const u16* __restrict__ ybuf, const float* __restrict__ ss, float* __restrict__ out)
{
  const int c = blockIdx.x, b = blockIdx.y, t = threadIdx.x;
  const float a = ss[c * 2], sh = ss[c * 2 + 1];
  const uint4* yp = (const uint4*)(ybuf + ((size_t)(b * NC + c)) * LQ);
  float4* op = (float4*)(out + ((size_t)(b * NC + c)) * LQ);
  for (int i = t; i < LQ / 8; i += 256) {
    union { uint4 u; u16 us[8]; } v;
    v.u = yp[i];
    float4 o0, o1;
    o0.x = a * h2f(v.us[0]) + sh; o0.y = a * h2f(v.us[1]) + sh;
    o0.z = a * h2f(v.us[2]) + sh; o0.w = a * h2f(v.us[3]) + sh;
    o1.x = a * h2f(v.us[4]) + sh; o1.y = a * h2f(v.us[5]) + sh;
    o1.z = a * h2f(v.us[6]) + sh; o1.w = a * h2f(v.us[7]) + sh;
    op[i * 2] = o0; op[i * 2 + 1] = o1;
  }
}

extern "C" void kernel_launch(void* const* d_in, const int* in_sizes, int n_in,
                              void* d_out, int out_size, void* d_ws, size_t ws_size,
                              hipStream_t stream)
{
  const float* x    = (const float*)d_in[0];
  const float* dwk  = (const float*)d_in[1];
  const float* g2   = (const float*)d_in[2];
  const float* b2   = (const float*)d_in[3];
  const float* pww  = (const float*)d_in[4];
  const float* pwb  = (const float*)d_in[5];
  const float* addw = (const float*)d_in[6];
  const float* g1   = (const float*)d_in[7];
  const float* b1   = (const float*)d_in[8];
  float* out = (float*)d_out;

  const size_t SQ = (size_t)NB * NC * LQ;   // 38,535,168
  const size_t SK = (size_t)NB * NC * LK;   //  9,633,792

  // Workspace (~157 MB): small buffers, then convq (77MB), then qbuf (77MB).
  // convk/convv/kbuf live INSIDE the qbuf region (dead before q-GEMM writes it;
  // k_kv is ordered before the q-GEMM to make that true).
  float* stats2 = (float*)d_ws;                       // 2304 f
  float* stats1 = stats2 + 3 * NC * 2;                // 768 f
  float* ss     = stats1 + NC * 2;                    // 768 f
  float* effb   = ss + NC * 2;                        // 1152 f
  float* kv     = effb + 3 * NC;                      // 393216 f
  u16* effw     = (u16*)(kv + (size_t)NB * NH * DHD * DHD);  // 442368 u16
  u16* convq    = effw + (size_t)3 * NC * NC;         // SQ u16
  u16* qbuf     = convq + SQ;                         // SQ u16 (q, then y in place)
  u16* convk    = qbuf;            // alias: dead before q-GEMM epilogue
  u16* convv    = qbuf + SK;       // alias
  u16* kbuf     = qbuf + 2 * SK;   // alias (3*SK = 57.8MB <= 77MB)
  u16* vbuf     = convk;           // alias (convk dead after k-GEMM)

  hipMemsetAsync(stats2, 0, (3 * NC * 2 + NC * 2) * sizeof(float), stream);

  k_dwconv<<<dim3(NC, NB), 256, 0, stream>>>(x, dwk, convq, convk, convv, stats2);
  k_foldbn<<<dim3(NC, 3), 128, 0, stream>>>(pww, pwb, g2, b2, stats2, effw, effb);
  k_pwgemm<<<dim3(7, 3, NB), 256, 0, stream>>>(convk, effw + (size_t)1 * NC * NC, effb + NC, kbuf, LK);
  k_pwgemm<<<dim3(7, 3, NB), 256, 0, stream>>>(convv, effw + (size_t)2 * NC * NC, effb + 2 * NC, vbuf, LK);
  k_kv<<<dim3(NH, NB), 256, 0, stream>>>(kbuf, vbuf, kv);
  k_pwgemm<<<dim3(25, 3, NB), 256, 0, stream>>>(convq, effw, effb, qbuf, LQ);
  k_att<<<dim3(13, NH, NB), 256, 0, stream>>>(qbuf, x, kv, addw, stats1);
  k_bn1coef<<<1, NC, 0, stream>>>(stats1, g1, b1, ss);
  k_bn1apply<<<dim3(NC, NB), 256, 0, stream>>>(qbuf, ss, out);
}

// Round 9
// 790.753 us; speedup vs baseline: 1.0393x; 1.0393x over previous
//
#include <hip/hip_runtime.h>

typedef unsigned short u16;
typedef unsigned int u32;

#define NB 32
#define NC 384
#define NH 12
#define DHD 32
#define HI 56
#define LQ 3136
#define HO 28
#define LK 784

typedef _Float16 half8 __attribute__((ext_vector_type(8)));
typedef float f32x4 __attribute__((ext_vector_type(4)));
typedef float f32x2 __attribute__((ext_vector_type(2)));

__device__ __forceinline__ u16 f2h(float f) {
  // clamp: finite even if upstream ever feeds garbage (diagnosability)
  f = fminf(fmaxf(f, -60000.f), 60000.f);
  union { _Float16 h; u16 u; } v; v.h = (_Float16)f; return v.u;
}
__device__ __forceinline__ float h2f(u16 u) {
  union { u16 u; _Float16 h; } v; v.u = u; return (float)v.h;
}
__device__ __forceinline__ float gelu(float x) {
  return 0.5f * x * (1.0f + erff(x * 0.70710678118654752440f));
}

// ---------------- K1: depthwise 3x3 conv, all 3 branches -------------------
// branch 0 (stride 1): store f16 conv-q + stats; branches 1,2: store + stats.
__global__ __launch_bounds__(256) void k_dwconv(
    const float* __restrict__ x, const float* __restrict__ dwk,
    u16* __restrict__ cq, u16* __restrict__ ck, u16* __restrict__ cv,
    float* __restrict__ stats2)
{
  const int c = blockIdx.x, b = blockIdx.y, t = threadIdx.x;
  __shared__ float pl[LQ];
  __shared__ float ker[32];
  __shared__ float redw[24];
  const float* xp = x + ((size_t)(b * NC + c)) * LQ;
  for (int i = t; i < LQ / 4; i += 256)
    ((float4*)pl)[i] = ((const float4*)xp)[i];
  if (t < 27) ker[t] = dwk[t * NC + c];
  __syncthreads();
  float s0 = 0, s1 = 0, s2 = 0, s3 = 0, s4 = 0, s5 = 0;
  u16* oq = cq + ((size_t)(b * NC + c)) * LQ;
  for (int p = t; p < LQ; p += 256) {
    const int h = p / HI, w = p - h * HI;
    float a = 0.f;
#pragma unroll
    for (int kh = 0; kh < 3; kh++) {
      const int hh = h + kh - 1;
      if (hh < 0 || hh >= HI) continue;
#pragma unroll
      for (int kw = 0; kw < 3; kw++) {
        const int ww = w + kw - 1;
        if (ww < 0 || ww >= HI) continue;
        a += ker[kh * 3 + kw] * pl[hh * HI + ww];
      }
    }
    const u16 rq = f2h(a);
    oq[p] = rq;
    const float ar = h2f(rq);   // stats on stored (rounded) value
    s0 += ar; s1 += ar * ar;
  }
  u16* ok = ck + ((size_t)(b * NC + c)) * LK;
  u16* ov = cv + ((size_t)(b * NC + c)) * LK;
  for (int p = t; p < LK; p += 256) {
    const int h = p / HO, w = p - h * HO;
    float ak = 0.f, av = 0.f;
#pragma unroll
    for (int kh = 0; kh < 3; kh++) {
      const int hh = 2 * h + kh - 1;
      if (hh < 0 || hh >= HI) continue;
#pragma unroll
      for (int kw = 0; kw < 3; kw++) {
        const int ww = 2 * w + kw - 1;
        if (ww < 0 || ww >= HI) continue;
        const float xv = pl[hh * HI + ww];
        ak += ker[9 + kh * 3 + kw] * xv;
        av += ker[18 + kh * 3 + kw] * xv;
      }
    }
    const u16 rk = f2h(ak), rv = f2h(av);
    ok[p] = rk; ov[p] = rv;
    const float akr = h2f(rk), avr = h2f(rv);
    s2 += akr; s3 += akr * akr; s4 += avr; s5 += avr * avr;
  }
  const int lane = t & 63, wv = t >> 6;
#pragma unroll
  for (int off = 32; off > 0; off >>= 1) {
    s0 += __shfl_down(s0, off); s1 += __shfl_down(s1, off);
    s2 += __shfl_down(s2, off); s3 += __shfl_down(s3, off);
    s4 += __shfl_down(s4, off); s5 += __shfl_down(s5, off);
  }
  if (lane == 0) {
    redw[wv * 6 + 0] = s0; redw[wv * 6 + 1] = s1; redw[wv * 6 + 2] = s2;
    redw[wv * 6 + 3] = s3; redw[wv * 6 + 4] = s4; redw[wv * 6 + 5] = s5;
  }
  __syncthreads();
  if (t < 6) {
    const float tot = redw[t] + redw[6 + t] + redw[12 + t] + redw[18 + t];
    const int br = t >> 1, which = t & 1;
    atomicAdd(&stats2[((br * NC) + c) * 2 + which], tot);
  }
}

// ---------------- K2: fold BN2 into pointwise weights ----------------------
__global__ __launch_bounds__(128) void k_foldbn(
    const float* __restrict__ pww, const float* __restrict__ pwb,
    const float* __restrict__ g2, const float* __restrict__ b2,
    const float* __restrict__ stats2,
    u16* __restrict__ effw, float* __restrict__ effb)
{
  const int o = blockIdx.x, br = blockIdx.y, t = threadIdx.x;
  const float cnt = (br == 0) ? (float)(NB * LQ) : (float)(NB * LK);
  __shared__ float red[128];
  float bacc = 0.f;
  for (int c = t; c < NC; c += 128) {
    const float S = stats2[((br * NC) + c) * 2 + 0];
    const float S2 = stats2[((br * NC) + c) * 2 + 1];
    const float mu = S / cnt;
    const float var = fmaxf(S2 / cnt - mu * mu, 0.f);
    const float a = g2[br * NC + c] * rsqrtf(var + 1e-5f);
    const float bs = b2[br * NC + c] - mu * a;
    const size_t wi = (size_t)br * NC * NC + (size_t)o * NC + c;
    const float wvv = pww[wi];
    effw[wi] = f2h(wvv * a);
    bacc += wvv * bs;
  }
  red[t] = bacc;
  __syncthreads();
  for (int off = 64; off > 0; off >>= 1) {
    if (t < off) red[t] += red[t + off];
    __syncthreads();
  }
  if (t == 0) effb[br * NC + o] = red[0] + pwb[br * NC + o];
}

// ---------------- K3: pointwise GEMM + bias + GELU (all branches) ----------
// B-staging: 2 k's packed per u32 write (static data idx), XOR column swizzle
// col = k ^ ((n>>3 & 3)<<3) -> write conflicts 16/32-way -> 4-way; read stays
// a contiguous b128 with the inverse swizzle folded into the quad index.
__global__ __launch_bounds__(256) void k_pwgemm(
    const u16* __restrict__ Y, const u16* __restrict__ W,
    const float* __restrict__ bias, u16* __restrict__ Out, const int N)
{
  const int nb = blockIdx.x * 128;
  const int mb = blockIdx.y * 128;
  const int b = blockIdx.z;
  const int t = threadIdx.x;
  const int lane = t & 63;
  const int wm = ((t >> 6) & 1) * 64, wn = ((t >> 6) >> 1) * 64;
  const int quad = lane >> 4, r16 = lane & 15;
  __shared__ u16 As[128 * 40];
  __shared__ u16 Bs[128 * 40];
  const u16* Yb = Y + (size_t)b * NC * N;
  f32x4 acc[4][4];
#pragma unroll
  for (int i = 0; i < 4; i++)
#pragma unroll
    for (int j = 0; j < 4; j++) acc[i][j] = (f32x4){0.f, 0.f, 0.f, 0.f};

  for (int k0 = 0; k0 < NC; k0 += 32) {
#pragma unroll
    for (int ld = 0; ld < 2; ld++) {
      const int cid = t + ld * 256;
      const int r = cid >> 2, q4 = cid & 3;
      const uint4 u = *(const uint4*)(W + (size_t)(mb + r) * NC + k0 + q4 * 8);
      *(uint4*)(&As[r * 40 + q4 * 8]) = u;
    }
    // B tile: one pass, 256 threads; thread = (k-pair kk2, n-octet q4)
    {
      const int kk2 = t >> 4;          // 0..15
      const int q4 = t & 15;           // 0..15
      const int n = nb + q4 * 8;
      union { uint4 u; u16 s[8]; } v0, v1;
      if (n < N) {
        const u16* yr0 = Yb + (size_t)(k0 + 2 * kk2) * N + n;
        v0.u = *(const uint4*)yr0;
        v1.u = *(const uint4*)(yr0 + N);
      } else {
        v0.u = make_uint4(0u, 0u, 0u, 0u);
        v1.u = make_uint4(0u, 0u, 0u, 0u);
      }
      const int col = (2 * kk2) ^ ((q4 & 3) << 3);
      u16* bp = &Bs[(q4 * 8) * 40 + col];
#pragma unroll
      for (int j = 0; j < 8; j++) {
        const u32 w = (u32)v0.s[j] | ((u32)v1.s[j] << 16);
        *(u32*)(bp + j * 40) = w;
      }
    }
    __syncthreads();
    half8 af[4], bfv[4];
#pragma unroll
    for (int sm = 0; sm < 4; sm++)
      af[sm] = *(const half8*)(&As[(wm + sm * 16 + r16) * 40 + quad * 8]);
#pragma unroll
    for (int sn = 0; sn < 4; sn++) {
      const int n = wn + sn * 16 + r16;
      bfv[sn] = *(const half8*)(&Bs[n * 40 + (((quad ^ (n >> 3)) & 3) << 3)]);
    }
#pragma unroll
    for (int sm = 0; sm < 4; sm++)
#pragma unroll
      for (int sn = 0; sn < 4; sn++)
        acc[sm][sn] = __builtin_amdgcn_mfma_f32_16x16x32_f16(af[sm], bfv[sn], acc[sm][sn], 0, 0, 0);
    __syncthreads();
  }
  u16* Ob = Out + (size_t)b * NC * N;
#pragma unroll
  for (int sm = 0; sm < 4; sm++) {
#pragma unroll
    for (int sn = 0; sn < 4; sn++) {
      const int n = nb + wn + sn * 16 + r16;
      if (n >= N) continue;
#pragma unroll
      for (int r = 0; r < 4; r++) {
        const int m = mb + wm + sm * 16 + quad * 4 + r;
        const float vv = gelu(acc[sm][sn][r] + bias[m]);
        Ob[(size_t)m * N + n] = f2h(vv);
      }
    }
  }
}

// ---------------- K4a: column softmax over k tokens + kv = ks^T v ----------
__global__ __launch_bounds__(256) void k_kv(
    const u16* __restrict__ kb_, const u16* __restrict__ vb_,
    float* __restrict__ kv)
{
  const int h = blockIdx.x, b = blockIdx.y;
  const int t = threadIdx.x, lane = t & 63, wv = t >> 6;
  __shared__ float mZ[64];
  __shared__ float ekt[128 * 33];
  __shared__ float vtt[128 * 33];
  const u16* kb = kb_ + ((size_t)(b * NC + h * DHD)) * LK;
  const u16* vb = vb_ + ((size_t)(b * NC + h * DHD)) * LK;
#pragma unroll
  for (int rr = 0; rr < 8; rr++) {
    const int d = wv * 8 + rr;
    const u16* row = kb + (size_t)d * LK;
    float mx = -1e30f;
    for (int l = lane; l < LK; l += 64) mx = fmaxf(mx, h2f(row[l]));
#pragma unroll
    for (int off = 32; off > 0; off >>= 1) mx = fmaxf(mx, __shfl_xor(mx, off));
    float se = 0.f;
    for (int l = lane; l < LK; l += 64) se += __expf(h2f(row[l]) - mx);
#pragma unroll
    for (int off = 32; off > 0; off >>= 1) se += __shfl_xor(se, off);
    if (lane == 0) { mZ[d] = mx; mZ[32 + d] = se; }
  }
  __syncthreads();
  const int d = t >> 3, e4 = (t & 7) * 4;
  float a0 = 0, a1 = 0, a2 = 0, a3 = 0;
  const int rr = t >> 3;
  const int ls = (t & 7) * 16;
  const u16* krow = kb + (size_t)rr * LK;
  const u16* vrow = vb + (size_t)rr * LK;
  const float mrow = mZ[rr];
  for (int l0 = 0; l0 < LK; l0 += 128) {
#pragma unroll
    for (int j = 0; j < 16; j++) {
      const int l = l0 + ls + j;
      const bool ok = l < LK;
      ekt[(ls + j) * 33 + rr] = ok ? __expf(h2f(krow[l]) - mrow) : 0.f;
      vtt[(ls + j) * 33 + rr] = ok ? h2f(vrow[l]) : 0.f;
    }
    __syncthreads();
    for (int lc = 0; lc < 128; lc++) {
      const float kd = ekt[lc * 33 + d];
      a0 += kd * vtt[lc * 33 + e4 + 0];
      a1 += kd * vtt[lc * 33 + e4 + 1];
      a2 += kd * vtt[lc * 33 + e4 + 2];
      a3 += kd * vtt[lc * 33 + e4 + 3];
    }
    __syncthreads();
  }
  const float rz = 1.0f / mZ[32 + d];
  float* kvp = kv + ((size_t)(b * NH + h) * DHD + d) * DHD + e4;
  kvp[0] = a0 * rz; kvp[1] = a1 * rz; kvp[2] = a2 * rz; kvp[3] = a3 * rz;
}

// ---------------- K4b: q softmax, att = qs*kv, residual, BN1 stats ---------
// 2 adjacent tokens per thread (R7-verified structure). Inner contraction
// vectorized as f32x2 so both tokens' FMAs fuse into v_pk_fma_f32
// (dual-issue packed f32; IEEE-identical per component).
__global__ __launch_bounds__(256) void k_att(
    u16* __restrict__ qy, const float* __restrict__ x,
    const float* __restrict__ kv, const float* __restrict__ addw,
    float* __restrict__ stats1)
{
  const int chunk = blockIdx.x, h = blockIdx.y, b = blockIdx.z;
  const int t = threadIdx.x;
  __shared__ float kvs[DHD * DHD];
  __shared__ float wred[4][64];
  const float* kvp = kv + (size_t)(b * NH + h) * (DHD * DHD);
  for (int i = t; i < DHD * DHD; i += 256) kvs[i] = kvp[i];
  float w0 = fmaxf(addw[0], 0.f);
  float w1 = fmaxf(addw[1], 0.f);
  const float wsum = w0 + w1 + 1e-12f;
  w0 /= wsum; w1 /= wsum;
  __syncthreads();
  const int l0 = chunk * 512 + 2 * t;       // even token; pair (l0, l0+1)
  const bool valid = (l0 + 1) < LQ;         // LQ even -> pair all-or-nothing
  const int lc = valid ? l0 : 0;
  u16* qp = qy + ((size_t)(b * NC + h * DHD)) * LQ + lc;
  const float* xp = x + ((size_t)(b * NC + h * DHD)) * LQ + lc;

  f32x2 acc2[DHD];
#pragma unroll
  for (int e = 0; e < DHD; e++) acc2[e] = (f32x2){0.f, 0.f};

  if (valid) {
    float p0[DHD], p1[DHD];
    float mx0 = -1e30f, mx1 = -1e30f;
#pragma unroll
    for (int d = 0; d < DHD; d++) {
      const u32 u = *(const u32*)(qp + (size_t)d * LQ);
      p0[d] = h2f((u16)(u & 0xffffu));
      p1[d] = h2f((u16)(u >> 16));
      mx0 = fmaxf(mx0, p0[d]); mx1 = fmaxf(mx1, p1[d]);
    }
    float se0 = 0.f, se1 = 0.f;
#pragma unroll
    for (int d = 0; d < DHD; d++) {
      p0[d] = __expf(p0[d] - mx0); se0 += p0[d];
      p1[d] = __expf(p1[d] - mx1); se1 += p1[d];
    }
    const float rs0 = 1.0f / se0, rs1 = 1.0f / se1;
    for (int d = 0; d < DHD; d++) {
      const f32x2 s01 = (f32x2){p0[d] * rs0, p1[d] * rs1};
      const float* kr = &kvs[d * DHD];
#pragma unroll
      for (int e = 0; e < DHD; e++) {
        acc2[e] += s01 * kr[e];   // v_pk_fma_f32: both tokens per instr
      }
    }
  }

  // epilogue: residual + store (f16) + fused BN1 partial stats
  const int lane = t & 63, wv = t >> 6;
#pragma unroll
  for (int e = 0; e < DHD; e++) {
    float v0 = 0.f, v1 = 0.f;
    if (valid) {
      const float2 xv = *(const float2*)(xp + (size_t)e * LQ);
      const float y0 = w0 * acc2[e][0] + w1 * xv.x;
      const float y1 = w0 * acc2[e][1] + w1 * xv.y;
      const u16 r0 = f2h(y0), r1 = f2h(y1);
      *(u32*)(qp + (size_t)e * LQ) = (u32)r0 | ((u32)r1 << 16);
      v0 = h2f(r0); v1 = h2f(r1);     // stats on stored (rounded) values
    }
    float s = v0 + v1, q = v0 * v0 + v1 * v1;
#pragma unroll
    for (int off = 32; off > 0; off >>= 1) {
      s += __shfl_down(s, off); q += __shfl_down(q, off);
    }
    if (lane == 0) { wred[wv][e] = s; wred[wv][32 + e] = q; }
  }
  __syncthreads();
  if (t < 64) {
    const float tot = wred[0][t] + wred[1][t] + wred[2][t] + wred[3][t];
    const int e = t & 31, which = t >> 5;
    atomicAdd(&stats1[(h * DHD + e) * 2 + which], tot);
  }
}

// ---------------- K5: BN1 coefficients -------------------------------------
__global__ void k_bn1coef(const float* __restrict__ stats1,
                          const float* __restrict__ g1, const float* __restrict__ b1,
                          float* __restrict__ ss)
{
  const int c = threadIdx.x;
  if (c >= NC) return;
  const float cnt = (float)NB * (float)LQ;
  const float S = stats1[c * 2], S2 = stats1[c * 2 + 1];
  const float mu = S / cnt;
  const float var = fmaxf(S2 / cnt - mu * mu, 0.f);
  const float a = g1[c] * rsqrtf(var + 1e-5f);
  ss[c * 2] = a;
  ss[c * 2 + 1] = b1[c] - mu * a;
}

// ---------------- K6: apply BN1, write fp32 output -------------------------
__global__ __launch_bounds__(256) void k_bn1apply(
    const u16* __restrict__ ybuf, const float* __restrict__ ss, float* __restrict__ out)
{
  const int c = blockIdx.x, b = blockIdx.y, t = threadIdx.x;
  const float a = ss[c * 2], sh = ss[c * 2 + 1];
  const uint4* yp = (const uint4*)(ybuf + ((size_t)(b * NC + c)) * LQ);
  float4* op = (float4*)(out + ((size_t)(b * NC + c)) * LQ);
  for (int i = t; i < LQ / 8; i += 256) {
    union { uint4 u; u16 us[8]; } v;
    v.u = yp[i];
    float4 o0, o1;
    o0.x = a * h2f(v.us[0]) + sh; o0.y = a * h2f(v.us[1]) + sh;
    o0.z = a * h2f(v.us[2]) + sh; o0.w = a * h2f(v.us[3]) + sh;
    o1.x = a * h2f(v.us[4]) + sh; o1.y = a * h2f(v.us[5]) + sh;
    o1.z = a * h2f(v.us[6]) + sh; o1.w = a * h2f(v.us[7]) + sh;
    op[i * 2] = o0; op[i * 2 + 1] = o1;
  }
}

extern "C" void kernel_launch(void* const* d_in, const int* in_sizes, int n_in,
                              void* d_out, int out_size, void* d_ws, size_t ws_size,
                              hipStream_t stream)
{
  const float* x    = (const float*)d_in[0];
  const float* dwk  = (const float*)d_in[1];
  const float* g2   = (const float*)d_in[2];
  const float* b2   = (const float*)d_in[3];
  const float* pww  = (const float*)d_in[4];
  const float* pwb  = (const float*)d_in[5];
  const float* addw = (const float*)d_in[6];
  const float* g1   = (const float*)d_in[7];
  const float* b1   = (const float*)d_in[8];
  float* out = (float*)d_out;

  const size_t SQ = (size_t)NB * NC * LQ;   // 38,535,168
  const size_t SK = (size_t)NB * NC * LK;   //  9,633,792

  // Workspace (~157 MB): small buffers, then convq (77MB), then qbuf (77MB).
  // convk/convv/kbuf live INSIDE the qbuf region (dead before q-GEMM writes it;
  // k_kv is ordered before the q-GEMM to make that true).
  float* stats2 = (float*)d_ws;                       // 2304 f
  float* stats1 = stats2 + 3 * NC * 2;                // 768 f
  float* ss     = stats1 + NC * 2;                    // 768 f
  float* effb   = ss + NC * 2;                        // 1152 f
  float* kv     = effb + 3 * NC;                      // 393216 f
  u16* effw     = (u16*)(kv + (size_t)NB * NH * DHD * DHD);  // 442368 u16
  u16* convq    = effw + (size_t)3 * NC * NC;         // SQ u16
  u16* qbuf     = convq + SQ;                         // SQ u16 (q, then y in place)
  u16* convk    = qbuf;            // alias: dead before q-GEMM epilogue
  u16* convv    = qbuf + SK;       // alias
  u16* kbuf     = qbuf + 2 * SK;   // alias (3*SK = 57.8MB <= 77MB)
  u16* vbuf     = convk;           // alias (convk dead after k-GEMM)

  hipMemsetAsync(stats2, 0, (3 * NC * 2 + NC * 2) * sizeof(float), stream);

  k_dwconv<<<dim3(NC, NB), 256, 0, stream>>>(x, dwk, convq, convk, convv, stats2);
  k_foldbn<<<dim3(NC, 3), 128, 0, stream>>>(pww, pwb, g2, b2, stats2, effw, effb);
  k_pwgemm<<<dim3(7, 3, NB), 256, 0, stream>>>(convk, effw + (size_t)1 * NC * NC, effb + NC, kbuf, LK);
  k_pwgemm<<<dim3(7, 3, NB), 256, 0, stream>>>(convv, effw + (size_t)2 * NC * NC, effb + 2 * NC, vbuf, LK);
  k_kv<<<dim3(NH, NB), 256, 0, stream>>>(kbuf, vbuf, kv);
  k_pwgemm<<<dim3(25, 3, NB), 256, 0, stream>>>(convq, effw, effb, qbuf, LQ);
  k_att<<<dim3(7, NH, NB), 256, 0, stream>>>(qbuf, x, kv, addw, stats1);
  k_bn1coef<<<1, NC, 0, stream>>>(stats1, g1, b1, ss);
  k_bn1apply<<<dim3(NC, NB), 256, 0, stream>>>(qbuf, ss, out);
}

// Round 10
// 762.173 us; speedup vs baseline: 1.0783x; 1.0375x over previous
//
#include <hip/hip_runtime.h>

typedef unsigned short u16;
typedef unsigned int u32;

#define NB 32
#define NC 384
#define NH 12
#define DHD 32
#define HI 56
#define LQ 3136
#define HO 28
#define LK 784

typedef _Float16 half8 __attribute__((ext_vector_type(8)));
typedef float f32x4 __attribute__((ext_vector_type(4)));

__device__ __forceinline__ u16 f2h(float f) {
  // clamp: finite even if upstream ever feeds garbage (diagnosability)
  f = fminf(fmaxf(f, -60000.f), 60000.f);
  union { _Float16 h; u16 u; } v; v.h = (_Float16)f; return v.u;
}
__device__ __forceinline__ float h2f(u16 u) {
  union { u16 u; _Float16 h; } v; v.u = u; return (float)v.h;
}
__device__ __forceinline__ float gelu(float x) {
  return 0.5f * x * (1.0f + erff(x * 0.70710678118654752440f));
}

// ---------------- K1: depthwise 3x3 conv, all 3 branches -------------------
// branch 0 (stride 1): store f16 conv-q + stats; branches 1,2: store + stats.
__global__ __launch_bounds__(256) void k_dwconv(
    const float* __restrict__ x, const float* __restrict__ dwk,
    u16* __restrict__ cq, u16* __restrict__ ck, u16* __restrict__ cv,
    float* __restrict__ stats2)
{
  const int c = blockIdx.x, b = blockIdx.y, t = threadIdx.x;
  __shared__ float pl[LQ];
  __shared__ float ker[32];
  __shared__ float redw[24];
  const float* xp = x + ((size_t)(b * NC + c)) * LQ;
  for (int i = t; i < LQ / 4; i += 256)
    ((float4*)pl)[i] = ((const float4*)xp)[i];
  if (t < 27) ker[t] = dwk[t * NC + c];
  __syncthreads();
  float s0 = 0, s1 = 0, s2 = 0, s3 = 0, s4 = 0, s5 = 0;
  u16* oq = cq + ((size_t)(b * NC + c)) * LQ;
  for (int p = t; p < LQ; p += 256) {
    const int h = p / HI, w = p - h * HI;
    float a = 0.f;
#pragma unroll
    for (int kh = 0; kh < 3; kh++) {
      const int hh = h + kh - 1;
      if (hh < 0 || hh >= HI) continue;
#pragma unroll
      for (int kw = 0; kw < 3; kw++) {
        const int ww = w + kw - 1;
        if (ww < 0 || ww >= HI) continue;
        a += ker[kh * 3 + kw] * pl[hh * HI + ww];
      }
    }
    const u16 rq = f2h(a);
    oq[p] = rq;
    const float ar = h2f(rq);   // stats on stored (rounded) value
    s0 += ar; s1 += ar * ar;
  }
  u16* ok = ck + ((size_t)(b * NC + c)) * LK;
  u16* ov = cv + ((size_t)(b * NC + c)) * LK;
  for (int p = t; p < LK; p += 256) {
    const int h = p / HO, w = p - h * HO;
    float ak = 0.f, av = 0.f;
#pragma unroll
    for (int kh = 0; kh < 3; kh++) {
      const int hh = 2 * h + kh - 1;
      if (hh < 0 || hh >= HI) continue;
#pragma unroll
      for (int kw = 0; kw < 3; kw++) {
        const int ww = 2 * w + kw - 1;
        if (ww < 0 || ww >= HI) continue;
        const float xv = pl[hh * HI + ww];
        ak += ker[9 + kh * 3 + kw] * xv;
        av += ker[18 + kh * 3 + kw] * xv;
      }
    }
    const u16 rk = f2h(ak), rv = f2h(av);
    ok[p] = rk; ov[p] = rv;
    const float akr = h2f(rk), avr = h2f(rv);
    s2 += akr; s3 += akr * akr; s4 += avr; s5 += avr * avr;
  }
  const int lane = t & 63, wv = t >> 6;
#pragma unroll
  for (int off = 32; off > 0; off >>= 1) {
    s0 += __shfl_down(s0, off); s1 += __shfl_down(s1, off);
    s2 += __shfl_down(s2, off); s3 += __shfl_down(s3, off);
    s4 += __shfl_down(s4, off); s5 += __shfl_down(s5, off);
  }
  if (lane == 0) {
    redw[wv * 6 + 0] = s0; redw[wv * 6 + 1] = s1; redw[wv * 6 + 2] = s2;
    redw[wv * 6 + 3] = s3; redw[wv * 6 + 4] = s4; redw[wv * 6 + 5] = s5;
  }
  __syncthreads();
  if (t < 6) {
    const float tot = redw[t] + redw[6 + t] + redw[12 + t] + redw[18 + t];
    const int br = t >> 1, which = t & 1;
    atomicAdd(&stats2[((br * NC) + c) * 2 + which], tot);
  }
}

// ---------------- K2: fold BN2 into pointwise weights ----------------------
__global__ __launch_bounds__(128) void k_foldbn(
    const float* __restrict__ pww, const float* __restrict__ pwb,
    const float* __restrict__ g2, const float* __restrict__ b2,
    const float* __restrict__ stats2,
    u16* __restrict__ effw, float* __restrict__ effb)
{
  const int o = blockIdx.x, br = blockIdx.y, t = threadIdx.x;
  const float cnt = (br == 0) ? (float)(NB * LQ) : (float)(NB * LK);
  __shared__ float red[128];
  float bacc = 0.f;
  for (int c = t; c < NC; c += 128) {
    const float S = stats2[((br * NC) + c) * 2 + 0];
    const float S2 = stats2[((br * NC) + c) * 2 + 1];
    const float mu = S / cnt;
    const float var = fmaxf(S2 / cnt - mu * mu, 0.f);
    const float a = g2[br * NC + c] * rsqrtf(var + 1e-5f);
    const float bs = b2[br * NC + c] - mu * a;
    const size_t wi = (size_t)br * NC * NC + (size_t)o * NC + c;
    const float wvv = pww[wi];
    effw[wi] = f2h(wvv * a);
    bacc += wvv * bs;
  }
  red[t] = bacc;
  __syncthreads();
  for (int off = 64; off > 0; off >>= 1) {
    if (t < off) red[t] += red[t + off];
    __syncthreads();
  }
  if (t == 0) effb[br * NC + o] = red[0] + pwb[br * NC + o];
}

// ---------------- K3: pointwise GEMM + bias + GELU (all branches) ----------
// B-staging: 2 k's packed per u32 write (static data idx), XOR column swizzle
// col = k ^ ((n>>3 & 3)<<3) -> write conflicts 16/32-way -> 4-way; read stays
// a contiguous b128 with the inverse swizzle folded into the quad index.
__global__ __launch_bounds__(256) void k_pwgemm(
    const u16* __restrict__ Y, const u16* __restrict__ W,
    const float* __restrict__ bias, u16* __restrict__ Out, const int N)
{
  const int nb = blockIdx.x * 128;
  const int mb = blockIdx.y * 128;
  const int b = blockIdx.z;
  const int t = threadIdx.x;
  const int lane = t & 63;
  const int wm = ((t >> 6) & 1) * 64, wn = ((t >> 6) >> 1) * 64;
  const int quad = lane >> 4, r16 = lane & 15;
  __shared__ u16 As[128 * 40];
  __shared__ u16 Bs[128 * 40];
  const u16* Yb = Y + (size_t)b * NC * N;
  f32x4 acc[4][4];
#pragma unroll
  for (int i = 0; i < 4; i++)
#pragma unroll
    for (int j = 0; j < 4; j++) acc[i][j] = (f32x4){0.f, 0.f, 0.f, 0.f};

  for (int k0 = 0; k0 < NC; k0 += 32) {
#pragma unroll
    for (int ld = 0; ld < 2; ld++) {
      const int cid = t + ld * 256;
      const int r = cid >> 2, q4 = cid & 3;
      const uint4 u = *(const uint4*)(W + (size_t)(mb + r) * NC + k0 + q4 * 8);
      *(uint4*)(&As[r * 40 + q4 * 8]) = u;
    }
    // B tile: one pass, 256 threads; thread = (k-pair kk2, n-octet q4)
    {
      const int kk2 = t >> 4;          // 0..15
      const int q4 = t & 15;           // 0..15
      const int n = nb + q4 * 8;
      union { uint4 u; u16 s[8]; } v0, v1;
      if (n < N) {
        const u16* yr0 = Yb + (size_t)(k0 + 2 * kk2) * N + n;
        v0.u = *(const uint4*)yr0;
        v1.u = *(const uint4*)(yr0 + N);
      } else {
        v0.u = make_uint4(0u, 0u, 0u, 0u);
        v1.u = make_uint4(0u, 0u, 0u, 0u);
      }
      const int col = (2 * kk2) ^ ((q4 & 3) << 3);
      u16* bp = &Bs[(q4 * 8) * 40 + col];
#pragma unroll
      for (int j = 0; j < 8; j++) {
        const u32 w = (u32)v0.s[j] | ((u32)v1.s[j] << 16);
        *(u32*)(bp + j * 40) = w;
      }
    }
    __syncthreads();
    half8 af[4], bfv[4];
#pragma unroll
    for (int sm = 0; sm < 4; sm++)
      af[sm] = *(const half8*)(&As[(wm + sm * 16 + r16) * 40 + quad * 8]);
#pragma unroll
    for (int sn = 0; sn < 4; sn++) {
      const int n = wn + sn * 16 + r16;
      bfv[sn] = *(const half8*)(&Bs[n * 40 + (((quad ^ (n >> 3)) & 3) << 3)]);
    }
#pragma unroll
    for (int sm = 0; sm < 4; sm++)
#pragma unroll
      for (int sn = 0; sn < 4; sn++)
        acc[sm][sn] = __builtin_amdgcn_mfma_f32_16x16x32_f16(af[sm], bfv[sn], acc[sm][sn], 0, 0, 0);
    __syncthreads();
  }
  u16* Ob = Out + (size_t)b * NC * N;
#pragma unroll
  for (int sm = 0; sm < 4; sm++) {
#pragma unroll
    for (int sn = 0; sn < 4; sn++) {
      const int n = nb + wn + sn * 16 + r16;
      if (n >= N) continue;
#pragma unroll
      for (int r = 0; r < 4; r++) {
        const int m = mb + wm + sm * 16 + quad * 4 + r;
        const float vv = gelu(acc[sm][sn][r] + bias[m]);
        Ob[(size_t)m * N + n] = f2h(vv);
      }
    }
  }
}

// ---------------- K4a: column softmax over k tokens + kv = ks^T v ----------
__global__ __launch_bounds__(256) void k_kv(
    const u16* __restrict__ kb_, const u16* __restrict__ vb_,
    float* __restrict__ kv)
{
  const int h = blockIdx.x, b = blockIdx.y;
  const int t = threadIdx.x, lane = t & 63, wv = t >> 6;
  __shared__ float mZ[64];
  __shared__ float ekt[128 * 33];
  __shared__ float vtt[128 * 33];
  const u16* kb = kb_ + ((size_t)(b * NC + h * DHD)) * LK;
  const u16* vb = vb_ + ((size_t)(b * NC + h * DHD)) * LK;
#pragma unroll
  for (int rr = 0; rr < 8; rr++) {
    const int d = wv * 8 + rr;
    const u16* row = kb + (size_t)d * LK;
    float mx = -1e30f;
    for (int l = lane; l < LK; l += 64) mx = fmaxf(mx, h2f(row[l]));
#pragma unroll
    for (int off = 32; off > 0; off >>= 1) mx = fmaxf(mx, __shfl_xor(mx, off));
    float se = 0.f;
    for (int l = lane; l < LK; l += 64) se += __expf(h2f(row[l]) - mx);
#pragma unroll
    for (int off = 32; off > 0; off >>= 1) se += __shfl_xor(se, off);
    if (lane == 0) { mZ[d] = mx; mZ[32 + d] = se; }
  }
  __syncthreads();
  const int d = t >> 3, e4 = (t & 7) * 4;
  float a0 = 0, a1 = 0, a2 = 0, a3 = 0;
  const int rr = t >> 3;
  const int ls = (t & 7) * 16;
  const u16* krow = kb + (size_t)rr * LK;
  const u16* vrow = vb + (size_t)rr * LK;
  const float mrow = mZ[rr];
  for (int l0 = 0; l0 < LK; l0 += 128) {
#pragma unroll
    for (int j = 0; j < 16; j++) {
      const int l = l0 + ls + j;
      const bool ok = l < LK;
      ekt[(ls + j) * 33 + rr] = ok ? __expf(h2f(krow[l]) - mrow) : 0.f;
      vtt[(ls + j) * 33 + rr] = ok ? h2f(vrow[l]) : 0.f;
    }
    __syncthreads();
    for (int lc = 0; lc < 128; lc++) {
      const float kd = ekt[lc * 33 + d];
      a0 += kd * vtt[lc * 33 + e4 + 0];
      a1 += kd * vtt[lc * 33 + e4 + 1];
      a2 += kd * vtt[lc * 33 + e4 + 2];
      a3 += kd * vtt[lc * 33 + e4 + 3];
    }
    __syncthreads();
  }
  const float rz = 1.0f / mZ[32 + d];
  float* kvp = kv + ((size_t)(b * NH + h) * DHD + d) * DHD + e4;
  kvp[0] = a0 * rz; kvp[1] = a1 * rz; kvp[2] = a2 * rz; kvp[3] = a3 * rz;
}

// ---------------- K4b: q softmax, att = qs*kv, residual, BN1 stats ---------
// 2 adjacent tokens per thread (R7-verified inner). Epilogue stats use a
// 2-level shuffle + per-wave LDS tile + own-tile column reduce instead of a
// 6-level shuffle tree per e: 384 bpermutes/thread -> ~132, chain depth 6->2,
// so the x-load/y-store stream is no longer stalled behind shuffle chains.
__global__ __launch_bounds__(256) void k_att(
    u16* __restrict__ qy, const float* __restrict__ x,
    const float* __restrict__ kv, const float* __restrict__ addw,
    float* __restrict__ stats1)
{
  const int chunk = blockIdx.x, h = blockIdx.y, b = blockIdx.z;
  const int t = threadIdx.x;
  __shared__ float kvs[DHD * DHD];
  __shared__ float2 st16[4][DHD][17];
  __shared__ float wred[4][64];
  const float* kvp = kv + (size_t)(b * NH + h) * (DHD * DHD);
  for (int i = t; i < DHD * DHD; i += 256) kvs[i] = kvp[i];
  float w0 = fmaxf(addw[0], 0.f);
  float w1 = fmaxf(addw[1], 0.f);
  const float wsum = w0 + w1 + 1e-12f;
  w0 /= wsum; w1 /= wsum;
  __syncthreads();
  const int l0 = chunk * 512 + 2 * t;       // even token; pair (l0, l0+1)
  const bool valid = (l0 + 1) < LQ;         // LQ even -> pair all-or-nothing
  const int lc = valid ? l0 : 0;
  u16* qp = qy + ((size_t)(b * NC + h * DHD)) * LQ + lc;
  const float* xp = x + ((size_t)(b * NC + h * DHD)) * LQ + lc;

  float acc0[DHD], acc1[DHD];
#pragma unroll
  for (int e = 0; e < DHD; e++) { acc0[e] = 0.f; acc1[e] = 0.f; }

  if (valid) {
    float p0[DHD], p1[DHD];
    float mx0 = -1e30f, mx1 = -1e30f;
#pragma unroll
    for (int d = 0; d < DHD; d++) {
      const u32 u = *(const u32*)(qp + (size_t)d * LQ);
      p0[d] = h2f((u16)(u & 0xffffu));
      p1[d] = h2f((u16)(u >> 16));
      mx0 = fmaxf(mx0, p0[d]); mx1 = fmaxf(mx1, p1[d]);
    }
    float se0 = 0.f, se1 = 0.f;
#pragma unroll
    for (int d = 0; d < DHD; d++) {
      p0[d] = __expf(p0[d] - mx0); se0 += p0[d];
      p1[d] = __expf(p1[d] - mx1); se1 += p1[d];
    }
    const float rs0 = 1.0f / se0, rs1 = 1.0f / se1;
    for (int d = 0; d < DHD; d++) {
      const float s0 = p0[d] * rs0, s1 = p1[d] * rs1;
      const float* kr = &kvs[d * DHD];
#pragma unroll
      for (int e = 0; e < DHD; e++) {
        const float kd = kr[e];
        acc0[e] += s0 * kd; acc1[e] += s1 * kd;
      }
    }
  }

  // epilogue: residual + store (f16) + light stats partials
  const int lane = t & 63, wv = t >> 6;
#pragma unroll
  for (int e = 0; e < DHD; e++) {
    float v0 = 0.f, v1 = 0.f;
    if (valid) {
      const float2 xv = *(const float2*)(xp + (size_t)e * LQ);
      const float y0 = w0 * acc0[e] + w1 * xv.x;
      const float y1 = w0 * acc1[e] + w1 * xv.y;
      const u16 r0 = f2h(y0), r1 = f2h(y1);
      *(u32*)(qp + (size_t)e * LQ) = (u32)r0 | ((u32)r1 << 16);
      v0 = h2f(r0); v1 = h2f(r1);     // stats on stored (rounded) values
    }
    float s = v0 + v1, q = v0 * v0 + v1 * v1;
    s += __shfl_down(s, 32); q += __shfl_down(q, 32);
    s += __shfl_down(s, 16); q += __shfl_down(q, 16);
    if (lane < 16) st16[wv][e][lane] = make_float2(s, q);
  }
  // each wave reduces ITS OWN tile (col = t>>1 -> source wave == wv), so
  // same-wave LDS ordering suffices; no barrier needed here.
  {
    const int col = t >> 1;          // 0..127 ; col>>5 == wv by construction
    const int wvs = col >> 5;
    const int es = col & 31;
    const int half = t & 1;
    float s = 0.f, q = 0.f;
#pragma unroll
    for (int i = 0; i < 8; i++) {
      const float2 v = st16[wvs][es][half * 8 + i];
      s += v.x; q += v.y;
    }
    s += __shfl_down(s, 1); q += __shfl_down(q, 1);
    if (half == 0) { wred[wvs][es] = s; wred[wvs][32 + es] = q; }
  }
  __syncthreads();
  if (t < 64) {
    const float tot = wred[0][t] + wred[1][t] + wred[2][t] + wred[3][t];
    const int e = t & 31, which = t >> 5;
    atomicAdd(&stats1[(h * DHD + e) * 2 + which], tot);
  }
}

// ---------------- K5: BN1 coefficients -------------------------------------
__global__ void k_bn1coef(const float* __restrict__ stats1,
                          const float* __restrict__ g1, const float* __restrict__ b1,
                          float* __restrict__ ss)
{
  const int c = threadIdx.x;
  if (c >= NC) return;
  const float cnt = (float)NB * (float)LQ;
  const float S = stats1[c * 2], S2 = stats1[c * 2 + 1];
  const float mu = S / cnt;
  const float var = fmaxf(S2 / cnt - mu * mu, 0.f);
  const float a = g1[c] * rsqrtf(var + 1e-5f);
  ss[c * 2] = a;
  ss[c * 2 + 1] = b1[c] - mu * a;
}

// ---------------- K6: apply BN1, write fp32 output -------------------------
__global__ __launch_bounds__(256) void k_bn1apply(
    const u16* __restrict__ ybuf, const float* __restrict__ ss, float* __restrict__ out)
{
  const int c = blockIdx.x, b = blockIdx.y, t = threadIdx.x;
  const float a = ss[c * 2], sh = ss[c * 2 + 1];
  const uint4* yp = (const uint4*)(ybuf + ((size_t)(b * NC + c)) * LQ);
  float4* op = (float4*)(out + ((size_t)(b * NC + c)) * LQ);
  for (int i = t; i < LQ / 8; i += 256) {
    union { uint4 u; u16 us[8]; } v;
    v.u = yp[i];
    float4 o0, o1;
    o0.x = a * h2f(v.us[0]) + sh; o0.y = a * h2f(v.us[1]) + sh;
    o0.z = a * h2f(v.us[2]) + sh; o0.w = a * h2f(v.us[3]) + sh;
    o1.x = a * h2f(v.us[4]) + sh; o1.y = a * h2f(v.us[5]) + sh;
    o1.z = a * h2f(v.us[6]) + sh; o1.w = a * h2f(v.us[7]) + sh;
    op[i * 2] = o0; op[i * 2 + 1] = o1;
  }
}

extern "C" void kernel_launch(void* const* d_in, const int* in_sizes, int n_in,
                              void* d_out, int out_size, void* d_ws, size_t ws_size,
                              hipStream_t stream)
{
  const float* x    = (const float*)d_in[0];
  const float* dwk  = (const float*)d_in[1];
  const float* g2   = (const float*)d_in[2];
  const float* b2   = (const float*)d_in[3];
  const float* pww  = (const float*)d_in[4];
  const float* pwb  = (const float*)d_in[5];
  const float* addw = (const float*)d_in[6];
  const float* g1   = (const float*)d_in[7];
  const float* b1   = (const float*)d_in[8];
  float* out = (float*)d_out;

  const size_t SQ = (size_t)NB * NC * LQ;   // 38,535,168
  const size_t SK = (size_t)NB * NC * LK;   //  9,633,792

  // Workspace (~157 MB): small buffers, then convq (77MB), then qbuf (77MB).
  // convk/convv/kbuf live INSIDE the qbuf region (dead before q-GEMM writes it;
  // k_kv is ordered before the q-GEMM to make that true).
  float* stats2 = (float*)d_ws;                       // 2304 f
  float* stats1 = stats2 + 3 * NC * 2;                // 768 f
  float* ss     = stats1 + NC * 2;                    // 768 f
  float* effb   = ss + NC * 2;                        // 1152 f
  float* kv     = effb + 3 * NC;                      // 393216 f
  u16* effw     = (u16*)(kv + (size_t)NB * NH * DHD * DHD);  // 442368 u16
  u16* convq    = effw + (size_t)3 * NC * NC;         // SQ u16
  u16* qbuf     = convq + SQ;                         // SQ u16 (q, then y in place)
  u16* convk    = qbuf;            // alias: dead before q-GEMM epilogue
  u16* convv    = qbuf + SK;       // alias
  u16* kbuf     = qbuf + 2 * SK;   // alias (3*SK = 57.8MB <= 77MB)
  u16* vbuf     = convk;           // alias (convk dead after k-GEMM)

  hipMemsetAsync(stats2, 0, (3 * NC * 2 + NC * 2) * sizeof(float), stream);

  k_dwconv<<<dim3(NC, NB), 256, 0, stream>>>(x, dwk, convq, convk, convv, stats2);
  k_foldbn<<<dim3(NC, 3), 128, 0, stream>>>(pww, pwb, g2, b2, stats2, effw, effb);
  k_pwgemm<<<dim3(7, 3, NB), 256, 0, stream>>>(convk, effw + (size_t)1 * NC * NC, effb + NC, kbuf, LK);
  k_pwgemm<<<dim3(7, 3, NB), 256, 0, stream>>>(convv, effw + (size_t)2 * NC * NC, effb + 2 * NC, vbuf, LK);
  k_kv<<<dim3(NH, NB), 256, 0, stream>>>(kbuf, vbuf, kv);
  k_pwgemm<<<dim3(25, 3, NB), 256, 0, stream>>>(convq, effw, effb, qbuf, LQ);
  k_att<<<dim3(7, NH, NB), 256, 0, stream>>>(qbuf, x, kv, addw, stats1);
  k_bn1coef<<<1, NC, 0, stream>>>(stats1, g1, b1, ss);
  k_bn1apply<<<dim3(NC, NB), 256, 0, stream>>>(qbuf, ss, out);
}